// Round 2
// baseline (61.976 us; speedup 1.0000x reference)
//
#include <hip/hip_runtime.h>

// RecalcDistances: dist[v,k] = || select(nidx[v,k]>=0, coords[nidx[v,k]], 0) - coords[v] ||^2
// V=200000, K=64, C=4 (C hardcoded via float4; V,K derived from sizes).

__global__ __launch_bounds__(256) void RecalcDistances_kernel(
    const float4* __restrict__ coords,   // [V] float4
    const int4*   __restrict__ nidx,     // [V*K/4] int4
    float4*       __restrict__ out,      // [V*K/4] float4
    int total_groups,                    // V * K/4
    int groups_per_row)                  // K/4
{
    int tid = blockIdx.x * blockDim.x + threadIdx.x;
    if (tid >= total_groups) return;

    int v = tid / groups_per_row;
    float4 c = coords[v];
    int4 idx = nidx[tid];

    float4 r;
    {
        float4 n = (idx.x >= 0) ? coords[idx.x] : make_float4(0.f, 0.f, 0.f, 0.f);
        float dx = n.x - c.x, dy = n.y - c.y, dz = n.z - c.z, dw = n.w - c.w;
        r.x = dx * dx + dy * dy + dz * dz + dw * dw;
    }
    {
        float4 n = (idx.y >= 0) ? coords[idx.y] : make_float4(0.f, 0.f, 0.f, 0.f);
        float dx = n.x - c.x, dy = n.y - c.y, dz = n.z - c.z, dw = n.w - c.w;
        r.y = dx * dx + dy * dy + dz * dz + dw * dw;
    }
    {
        float4 n = (idx.z >= 0) ? coords[idx.z] : make_float4(0.f, 0.f, 0.f, 0.f);
        float dx = n.x - c.x, dy = n.y - c.y, dz = n.z - c.z, dw = n.w - c.w;
        r.z = dx * dx + dy * dy + dz * dz + dw * dw;
    }
    {
        float4 n = (idx.w >= 0) ? coords[idx.w] : make_float4(0.f, 0.f, 0.f, 0.f);
        float dx = n.x - c.x, dy = n.y - c.y, dz = n.z - c.z, dw = n.w - c.w;
        r.w = dx * dx + dy * dy + dz * dz + dw * dw;
    }

    out[tid] = r;
}

extern "C" void kernel_launch(void* const* d_in, const int* in_sizes, int n_in,
                              void* d_out, int out_size, void* d_ws, size_t ws_size,
                              hipStream_t stream) {
    const float4* coords = (const float4*)d_in[0];
    const int4*   nidx   = (const int4*)d_in[1];
    float4*       out    = (float4*)d_out;

    const int C = 4;
    int V = in_sizes[0] / C;          // 200000
    int K = in_sizes[1] / V;          // 64
    int groups_per_row = K / 4;       // 16
    int total_groups = V * groups_per_row;

    int block = 256;
    int grid = (total_groups + block - 1) / block;
    RecalcDistances_kernel<<<grid, block, 0, stream>>>(coords, nidx, out,
                                                       total_groups, groups_per_row);
}